// Round 2
// baseline (949.367 us; speedup 1.0000x reference)
//
#include <hip/hip_runtime.h>
#include <hip/hip_bf16.h>

#define NPTS 131072
#define DIMS 512
#define KC   1024

typedef _Float16 f16;
using f16x8  = __attribute__((ext_vector_type(8))) _Float16;
using f32x16 = __attribute__((ext_vector_type(16))) float;
typedef unsigned short u16;
typedef unsigned int u32;
typedef unsigned long long u64;

// ---- workspace layout (bytes) ----
#define CT_OFF     0ull            // Ct [1024][512] fp16 = 1 MB
#define CSQ_OFF    1048576ull      // 4 KB
#define CSQP_OFF   1052672ull      // 16*1024 floats = 64 KB
#define G1_OFF     1118208ull      // u64 x 131072 = 1 MB
#define G2_OFF     2166784ull      // 1 MB
#define CNT_OFF    3215360ull      // 256 B
#define LIST_OFF   3215616ull      // 512 KB
#define WS_NEEDED  3739904ull

#define MARGIN 0.2f

// ---------- helpers ----------
__device__ __forceinline__ u32 f2o(float f) {
    u32 u = __float_as_uint(f);
    return (u & 0x80000000u) ? ~u : (u | 0x80000000u);
}
__device__ __forceinline__ float o2f(u32 o) {
    u32 u = (o & 0x80000000u) ? (o & 0x7FFFFFFFu) : ~o;
    return __uint_as_float(u);
}
__device__ __forceinline__ u64 umin64(u64 a, u64 b) { return a < b ? a : b; }
__device__ __forceinline__ u64 umax64(u64 a, u64 b) { return a > b ? a : b; }

// global -> LDS direct (16B per lane). LDS dest is wave-uniform base + lane*16.
__device__ __forceinline__ void async_load16(const void* g, const void* l) {
    auto gp = reinterpret_cast<__attribute__((address_space(1))) void*>(
        reinterpret_cast<uintptr_t>(g));
    auto lp = reinterpret_cast<__attribute__((address_space(3))) void*>(
        (unsigned int)reinterpret_cast<uintptr_t>(l));
    __builtin_amdgcn_global_load_lds(gp, lp, 16, 0, 0);
}

// ---------- prepass: transpose C [512][1024] -> Ct [1024][512] fp16 + csq partials ----------
__global__ void split_c_kernel(const float* __restrict__ C,
                               u16* __restrict__ ct, float* __restrict__ csq_part) {
    __shared__ float t[32][33];
    int bn = blockIdx.x, bd = blockIdx.y;
    int tx = threadIdx.x & 31, ty = threadIdx.x >> 5;
#pragma unroll
    for (int r = 0; r < 32; r += 8)
        t[ty + r][tx] = C[(size_t)(bd * 32 + ty + r) * KC + bn * 32 + tx];
    __syncthreads();
#pragma unroll
    for (int r = 0; r < 32; r += 8) {
        int n = bn * 32 + ty + r, d = bd * 32 + tx;
        float v = t[tx][ty + r];
        f16 h = (f16)v;
        ct[(size_t)n * DIMS + d] = *reinterpret_cast<u16*>(&h);
        float sq = v * v;
#pragma unroll
        for (int m = 1; m < 32; m <<= 1)
            sq += __shfl_xor(sq, m, 64);
        if (tx == 0) csq_part[bd * KC + n] = sq;
    }
}

// ---------- csq: deterministic 16-part reduce ----------
__global__ void csq_reduce_kernel(const float* __restrict__ part, float* __restrict__ csq) {
    int k = blockIdx.x * 256 + threadIdx.x;
    float s = 0.f;
#pragma unroll
    for (int p = 0; p < 16; ++p) s += part[p * KC + k];
    csq[k] = s;
}

// ---------- fallback-only csq ----------
__global__ void csq_kernel(const float* __restrict__ C, float* __restrict__ csq) {
    int k = blockIdx.x * blockDim.x + threadIdx.x;
    if (k < KC) {
        float s = 0.f;
        for (int d = 0; d < DIMS; ++d) {
            float v = C[d * KC + k];
            s = fmaf(v, v, s);
        }
        csq[k] = s;
    }
}

// ---------- main: fp16 1-term MFMA GEMM, TRANSPOSED (M=centroids, N=points) ----------
// block 128(M=centroids) x 128(N=points), BK=32, 16 kt. 4 waves 2x2, wave tile 64x64
// (2mt x 2nt of 32x32x16). C/D col = lane = POINT, row = reg = CENTROID -> each lane
// holds 32 centroid candidates for one point in registers: top-2 is a register reduce
// (no 5-step u64 butterflies). A = Ct fp16 via global_load_lds; B = F fp32->fp16 in-kernel.
// LDS: A[0,8K) row*64B (centroid rows), B[8K,16K) row*64B (point rows).
// 16B chunks, pos = c ^ ((row>>1)&3) on both sides (global_load_lds: source pre-swizzled).
__global__ __launch_bounds__(256, 4) void gemm_argmin_kernel(
    const float* __restrict__ F, const u16* __restrict__ Ct,
    const float* __restrict__ csq, u64* __restrict__ g1, u64* __restrict__ g2)
{
    __shared__ __align__(16) uint8_t smem[16384];
    __shared__ float csq_l[128];

    const int tid  = threadIdx.x;
    const int lane = tid & 63;
    const int wid  = tid >> 6;
    const int wm   = wid >> 1, wn = wid & 1;
    // XCD swizzle: XCD = L%8 = py%8 -> each XCD owns whole point-tiles (F tile reused 8x via L2)
    const unsigned L = blockIdx.x;
    const int py = (int)((L & 7u) + 8u * (L >> 6));   // point tile 0..1023
    const int cx = (int)((L >> 3) & 7u);              // centroid tile 0..7

    if (tid < 128) csq_l[tid] = csq[cx * 128 + tid];

    f32x16 acc[2][2];
#pragma unroll
    for (int i = 0; i < 2; ++i)
#pragma unroll
        for (int j = 0; j < 2; ++j)
#pragma unroll
            for (int e = 0; e < 16; ++e) acc[i][j][e] = 0.f;

    // --- B staging (F/points): thread -> row = tid>>1 (0..127), h = tid&1 (16 floats)
    const int brow = tid >> 1, bh_ = tid & 1;
    const float* bF = F + (size_t)(py * 128 + brow) * DIMS + bh_ * 16;
    const int bxr = (brow >> 1) & 3;
    const unsigned bw0 = 8192u + (unsigned)(brow * 64 + (((bh_ * 2 + 0) ^ bxr) * 16));
    const unsigned bw1 = 8192u + (unsigned)(brow * 64 + (((bh_ * 2 + 1) ^ bxr) * 16));

    // --- A staging (Ct/centroids): 2 async calls/wave, each 16 rows x 64B. lane -> row' = lane>>2
    const int c_st = (lane & 3) ^ ((lane >> 3) & 3);
    const u16* aBase = Ct + (size_t)(cx * 128 + wid * 32 + (lane >> 2)) * DIMS + c_st * 8;
    const unsigned aw = (unsigned)(wid * 32) * 64;   // + lane*16 implied

    // --- fragment read offsets (identical layout both operands) ---
    const int kh = lane >> 5;
    const int cl = lane & 31;
    const int xr = (cl >> 1) & 3;
    const unsigned mb = (unsigned)cl * 64;
    const unsigned offs0 = mb + (unsigned)(((0 + kh) ^ xr) * 16);   // s=0: q=kh
    const unsigned offs1 = mb + (unsigned)(((2 + kh) ^ xr) * 16);   // s=1: q=2+kh

    for (int kt = 0; kt < DIMS / 32; ++kt) {
        const int k0 = kt * 32;
        // B global loads early (regs only)
        float4 f0 = *(const float4*)(bF + k0);
        float4 f1 = *(const float4*)(bF + k0 + 4);
        float4 f2 = *(const float4*)(bF + k0 + 8);
        float4 f3 = *(const float4*)(bF + k0 + 12);

        __syncthreads();   // prev iter frag reads done
        // A: 2 async 16B-per-lane loads (16 centroid rows each)
        async_load16(aBase + k0,             smem + aw);
        async_load16(aBase + 16 * DIMS + k0, smem + aw + 1024);
        // B: convert + swizzled store
        {
            float v[16] = {f0.x, f0.y, f0.z, f0.w, f1.x, f1.y, f1.z, f1.w,
                           f2.x, f2.y, f2.z, f2.w, f3.x, f3.y, f3.z, f3.w};
            f16x8 h0, h1;
#pragma unroll
            for (int i = 0; i < 8; ++i) h0[i] = (f16)v[i];
#pragma unroll
            for (int i = 0; i < 8; ++i) h1[i] = (f16)v[8 + i];
            *(f16x8*)(smem + bw0) = h0;
            *(f16x8*)(smem + bw1) = h1;
        }
        __syncthreads();   // stage visible (drains vmcnt)

#pragma unroll
        for (int s = 0; s < 2; ++s) {
            const unsigned off = s ? offs1 : offs0;
            f16x8 a[2], b[2];
#pragma unroll
            for (int mt = 0; mt < 2; ++mt)
                a[mt] = *(const f16x8*)(smem + wm * 4096 + mt * 2048 + off);
#pragma unroll
            for (int nt = 0; nt < 2; ++nt)
                b[nt] = *(const f16x8*)(smem + 8192 + wn * 4096 + nt * 2048 + off);
#pragma unroll
            for (int mt = 0; mt < 2; ++mt)
#pragma unroll
                for (int nt = 0; nt < 2; ++nt)
                    acc[mt][nt] = __builtin_amdgcn_mfma_f32_32x32x16_f16(a[mt], b[nt], acc[mt][nt], 0, 0, 0);
        }
    }

    __syncthreads();
    u64* tbl = (u64*)smem;   // [128 points][wm:2][top2:2] = 4 KB

    // C/D layout: col(point) = lane&31, row(centroid) = (reg&3) + 8*(reg>>2) + 4*kh
    // Each lane: top-2 over its 32 in-register centroid candidates, then one
    // shfl_xor(32) to merge the kh halves (other 64 centroid rows, same point).
#pragma unroll
    for (int nt = 0; nt < 2; ++nt) {
        u64 a = ~0ull, b = ~0ull;
#pragma unroll
        for (int mt = 0; mt < 2; ++mt)
#pragma unroll
            for (int reg = 0; reg < 16; ++reg) {
                const int rl = wm * 64 + mt * 32 + (reg & 3) + 8 * (reg >> 2) + 4 * kh;
                const float d = fmaf(-2.0f, acc[mt][nt][reg], csq_l[rl]);   // LDS broadcast read
                const u64 key = ((u64)f2o(d) << 32) | (u32)(cx * 128 + rl);
                const u64 t = umin64(a, key);                // branchless top-2 insert
                b = umin64(b, umax64(a, key));
                a = t;
            }
        const u64 oa = __shfl_xor(a, 32, 64);
        const u64 ob = __shfl_xor(b, 32, 64);
        const u64 lo = umin64(a, oa);
        const u64 bb = umin64(umax64(a, oa), umin64(b, ob));
        if (kh == 0) {
            const int p = wn * 64 + nt * 32 + cl;
            tbl[(p * 2 + wm) * 2 + 0] = lo;
            tbl[(p * 2 + wm) * 2 + 1] = bb;
        }
    }
    __syncthreads();

    if (tid < 128) {
        const u64 a0 = tbl[tid * 4 + 0], b0 = tbl[tid * 4 + 1];
        const u64 a1 = tbl[tid * 4 + 2], b1 = tbl[tid * 4 + 3];
        u64 m1 = umin64(a0, a1);
        u64 m2 = umin64(umax64(a0, a1), umin64(b0, b1));
        const size_t grow = (size_t)py * 128 + tid;
        u64 o = atomicMin(&g1[grow], m1);
        atomicMin(&g2[grow], (m1 < o) ? o : m1);
        atomicMin(&g2[grow], m2);
    }
}

// ---------- phase A: flag rows; LDS-aggregated compaction (1 global atomic / block) ----------
__global__ __launch_bounds__(256) void flag_compact_kernel(
    const u64* __restrict__ g1, const u64* __restrict__ g2,
    float* __restrict__ out, u32* __restrict__ cnt, u32* __restrict__ list)
{
    __shared__ u32 lcnt, lbase;
    __shared__ u32 lrows[256];
    const int tid = threadIdx.x;
    const int row = blockIdx.x * 256 + tid;
    if (tid == 0) lcnt = 0;
    __syncthreads();

    const u64 k1 = g1[row], k2 = g2[row];
    const float d1 = o2f((u32)(k1 >> 32));
    const float d2 = o2f((u32)(k2 >> 32));
    bool flagged = !(d2 - d1 > MARGIN);
    if (!flagged) {
        out[row] = (float)(u32)(k1 & 1023u);
    } else {
        u32 li = atomicAdd(&lcnt, 1u);
        lrows[li] = (u32)row;
    }
    __syncthreads();
    if (tid == 0 && lcnt > 0) lbase = atomicAdd(cnt, lcnt);
    __syncthreads();
    if (tid < lcnt) list[lbase + tid] = lrows[tid];
}

// ---------- phase B: exact fp32 argmin for flagged rows (work-stealing, 4 rows/batch) ----------
__global__ __launch_bounds__(256) void rescue2_kernel(
    const float* __restrict__ F, const float* __restrict__ C,
    const float* __restrict__ csq, const u32* __restrict__ cnt,
    const u32* __restrict__ list, u32* __restrict__ wptr, float* __restrict__ out)
{
    __shared__ float xs[4][512];
    __shared__ u64 wavemin[4][4];
    __shared__ int rows_s[4];

    const int tid = threadIdx.x;
    const int lane = tid & 63;
    const int wid = tid >> 6;
    const u32 n = cnt[0];

    for (;;) {
        __syncthreads();
        u32 base;
        if (tid == 0) {
            base = atomicAdd(wptr, 4u);
            rows_s[0] = (int)base;
        }
        __syncthreads();
        base = (u32)rows_s[0];
        if (base >= n) break;

        int rows[4];
#pragma unroll
        for (int j = 0; j < 4; ++j) {
            u32 idx = base + j;
            rows[j] = (int)list[idx < n ? idx : (n - 1)];
        }
#pragma unroll
        for (int j = 0; j < 4; ++j) {
            if (tid < 128)
                *(float4*)&xs[j][tid * 4] = *(const float4*)&F[(size_t)rows[j] * DIMS + tid * 4];
        }
        __syncthreads();

        float dot[4][4];
#pragma unroll
        for (int j = 0; j < 4; ++j)
#pragma unroll
            for (int q = 0; q < 4; ++q) dot[j][q] = 0.f;

#pragma unroll 4
        for (int d = 0; d < DIMS; ++d) {
            float cv[4];
#pragma unroll
            for (int q = 0; q < 4; ++q) cv[q] = C[d * KC + tid + 256 * q];
            float xv[4];
#pragma unroll
            for (int j = 0; j < 4; ++j) xv[j] = xs[j][d];
#pragma unroll
            for (int j = 0; j < 4; ++j)
#pragma unroll
                for (int q = 0; q < 4; ++q)
                    dot[j][q] = fmaf(xv[j], cv[q], dot[j][q]);
        }

#pragma unroll
        for (int j = 0; j < 4; ++j) {
            u64 best = ~0ull;
#pragma unroll
            for (int q = 0; q < 4; ++q) {
                const int k = tid + 256 * q;
                const float dist = csq[k] - 2.0f * dot[j][q];
                best = umin64(best, ((u64)f2o(dist) << 32) | (u32)k);
            }
#pragma unroll
            for (int off = 32; off > 0; off >>= 1)
                best = umin64(best, __shfl_xor(best, off, 64));
            if (lane == 0) wavemin[j][wid] = best;
        }
        __syncthreads();
        if (tid < 4) {
            const u32 idx = base + tid;
            if (idx < n) {
                u64 b = umin64(umin64(wavemin[tid][0], wavemin[tid][1]),
                               umin64(wavemin[tid][2], wavemin[tid][3]));
                out[list[idx]] = (float)(u32)(b & 0xFFFFFFFFull);
            }
        }
    }
}

// ================= fallback (fp32 vector path, used only if ws too small) =================
__global__ __launch_bounds__(256, 3) void assign_kernel_fp32(
    const float* __restrict__ F, const float* __restrict__ C,
    const float* __restrict__ csq, float* __restrict__ out)
{
    __shared__ float At[32][68];
    __shared__ float Bs[32 * 256];
    __shared__ u64 best_row[64];

    const int tid = threadIdx.x;
    const int tx = tid & 31;
    const int ty = tid >> 5;
    const int n0 = blockIdx.x * 64;

    if (tid < 64) best_row[tid] = ~0ull;

    u64 best[8];
#pragma unroll
    for (int r = 0; r < 8; ++r) best[r] = ~0ull;

    const int arow = tid >> 3;
    const int ac4  = tid & 7;
    const float* Atp = &At[0][ty * 8];
    const float* Bsp = &Bs[tx * 4];

    for (int kt = 0; kt < 4; ++kt) {
        float acc[8][8];
#pragma unroll
        for (int r = 0; r < 8; ++r)
#pragma unroll
            for (int j = 0; j < 8; ++j) acc[r][j] = 0.f;

        for (int dt = 0; dt < DIMS / 32; ++dt) {
            __syncthreads();
#pragma unroll
            for (int i = 0; i < 2; ++i) {
                int row = arow + 32 * i;
                float4 av = *(const float4*)&F[(long)(n0 + row) * DIMS + dt * 32 + ac4 * 4];
                At[ac4 * 4 + 0][row] = av.x;
                At[ac4 * 4 + 1][row] = av.y;
                At[ac4 * 4 + 2][row] = av.z;
                At[ac4 * 4 + 3][row] = av.w;
            }
#pragma unroll
            for (int i = 0; i < 8; ++i) {
                int idx = tid + 256 * i;
                int d  = idx >> 6;
                int c4 = idx & 63;
                float4 bv = *(const float4*)&C[(long)(dt * 32 + d) * KC + kt * 256 + c4 * 4];
                *(float4*)&Bs[d * 256 + c4 * 4] = bv;
            }
            __syncthreads();

#pragma unroll 8
            for (int dd = 0; dd < 32; ++dd) {
                float4 a0 = *(const float4*)(Atp + dd * 68);
                float4 a1 = *(const float4*)(Atp + dd * 68 + 4);
                float4 b0 = *(const float4*)(Bsp + dd * 256);
                float4 b1 = *(const float4*)(Bsp + dd * 256 + 128);
                float a[8] = {a0.x, a0.y, a0.z, a0.w, a1.x, a1.y, a1.z, a1.w};
                float bb[8] = {b0.x, b0.y, b0.z, b0.w, b1.x, b1.y, b1.z, b1.w};
#pragma unroll
                for (int r = 0; r < 8; ++r)
#pragma unroll
                    for (int j = 0; j < 8; ++j)
                        acc[r][j] = fmaf(a[r], bb[j], acc[r][j]);
            }
        }

        float4 cs0 = *(const float4*)&csq[kt * 256 + tx * 4];
        float4 cs1 = *(const float4*)&csq[kt * 256 + 128 + tx * 4];
        float cs[8] = {cs0.x, cs0.y, cs0.z, cs0.w, cs1.x, cs1.y, cs1.z, cs1.w};
#pragma unroll
        for (int j = 0; j < 8; ++j) {
            int k = kt * 256 + ((j < 4) ? (tx * 4 + j) : (128 + tx * 4 + (j - 4)));
#pragma unroll
            for (int r = 0; r < 8; ++r) {
                float val = cs[j] - 2.0f * acc[r][j];
                u64 key = ((u64)f2o(val) << 32) | (u64)(unsigned)k;
                if (key < best[r]) best[r] = key;
            }
        }
    }

#pragma unroll
    for (int r = 0; r < 8; ++r)
        atomicMin(&best_row[ty * 8 + r], best[r]);
    __syncthreads();

    if (tid < 64)
        out[n0 + tid] = (float)(unsigned)(best_row[tid] & 0xFFFFFFFFull);
}

// ================= launch =================
extern "C" void kernel_launch(void* const* d_in, const int* in_sizes, int n_in,
                              void* d_out, int out_size, void* d_ws, size_t ws_size,
                              hipStream_t stream) {
    const float* F = (const float*)d_in[0];   // [131072, 512]
    const float* C = (const float*)d_in[1];   // [512, 1024]
    float* out = (float*)d_out;               // [131072]
    char* ws = (char*)d_ws;

    if (ws_size < WS_NEEDED) {
        float* csq = (float*)d_ws;
        csq_kernel<<<KC / 256, 256, 0, stream>>>(C, csq);
        assign_kernel_fp32<<<NPTS / 64, 256, 0, stream>>>(F, C, csq, out);
        return;
    }

    u16* Ct = (u16*)(ws + CT_OFF);
    float* csq  = (float*)(ws + CSQ_OFF);
    float* csqp = (float*)(ws + CSQP_OFF);
    u64* g1 = (u64*)(ws + G1_OFF);
    u64* g2 = (u64*)(ws + G2_OFF);
    u32* cnt  = (u32*)(ws + CNT_OFF);
    u32* list = (u32*)(ws + LIST_OFF);

    hipMemsetAsync(g1, 0xFF, 2ull * NPTS * 8, stream);   // g1+g2 contiguous
    hipMemsetAsync(cnt, 0, 8, stream);
    split_c_kernel<<<dim3(KC / 32, DIMS / 32), 256, 0, stream>>>(C, Ct, csqp);
    csq_reduce_kernel<<<KC / 256, 256, 0, stream>>>(csqp, csq);
    gemm_argmin_kernel<<<8192, 256, 0, stream>>>(F, Ct, csq, g1, g2);
    flag_compact_kernel<<<NPTS / 256, 256, 0, stream>>>(g1, g2, out, cnt, list);
    rescue2_kernel<<<1024, 256, 0, stream>>>(F, C, csq, cnt, list, cnt + 1, out);
}

// Round 3
// 728.974 us; speedup vs baseline: 1.3023x; 1.3023x over previous
//
#include <hip/hip_runtime.h>
#include <hip/hip_bf16.h>

#define NPTS 131072
#define DIMS 512
#define KC   1024

typedef _Float16 f16;
using f16x8  = __attribute__((ext_vector_type(8))) _Float16;
using f32x16 = __attribute__((ext_vector_type(16))) float;
typedef unsigned short u16;
typedef unsigned int u32;
typedef unsigned long long u64;

// ---- workspace layout (bytes) ----
#define CT_OFF     0ull            // Ct [1024][512] fp16 = 1 MB
#define CSQ_OFF    1048576ull      // 4 KB
#define CSQP_OFF   1052672ull      // 16*1024 floats = 64 KB
#define CNT_OFF    1118208ull      // 256 B
#define LIST_OFF   1118464ull      // 512 KB
#define WS_NEEDED  1642752ull

#define MARGIN 0.2f

// ---------- helpers ----------
__device__ __forceinline__ u32 f2o(float f) {
    u32 u = __float_as_uint(f);
    return (u & 0x80000000u) ? ~u : (u | 0x80000000u);
}
__device__ __forceinline__ float o2f(u32 o) {
    u32 u = (o & 0x80000000u) ? (o & 0x7FFFFFFFu) : ~o;
    return __uint_as_float(u);
}
__device__ __forceinline__ u64 umin64(u64 a, u64 b) { return a < b ? a : b; }
__device__ __forceinline__ u64 umax64(u64 a, u64 b) { return a > b ? a : b; }

// global -> LDS direct (16B per lane). LDS dest is wave-uniform base + lane*16.
__device__ __forceinline__ void async_load16(const void* g, const void* l) {
    auto gp = reinterpret_cast<__attribute__((address_space(1))) void*>(
        reinterpret_cast<uintptr_t>(g));
    auto lp = reinterpret_cast<__attribute__((address_space(3))) void*>(
        (unsigned int)reinterpret_cast<uintptr_t>(l));
    __builtin_amdgcn_global_load_lds(gp, lp, 16, 0, 0);
}

// ---------- prepass: transpose C [512][1024] -> Ct [1024][512] fp16 + csq partials ----------
__global__ void split_c_kernel(const float* __restrict__ C,
                               u16* __restrict__ ct, float* __restrict__ csq_part) {
    __shared__ float t[32][33];
    int bn = blockIdx.x, bd = blockIdx.y;
    int tx = threadIdx.x & 31, ty = threadIdx.x >> 5;
#pragma unroll
    for (int r = 0; r < 32; r += 8)
        t[ty + r][tx] = C[(size_t)(bd * 32 + ty + r) * KC + bn * 32 + tx];
    __syncthreads();
#pragma unroll
    for (int r = 0; r < 32; r += 8) {
        int n = bn * 32 + ty + r, d = bd * 32 + tx;
        float v = t[tx][ty + r];
        f16 h = (f16)v;
        ct[(size_t)n * DIMS + d] = *reinterpret_cast<u16*>(&h);
        float sq = v * v;
#pragma unroll
        for (int m = 1; m < 32; m <<= 1)
            sq += __shfl_xor(sq, m, 64);
        if (tx == 0) csq_part[bd * KC + n] = sq;
    }
}

// ---------- csq: deterministic 16-part reduce ----------
__global__ void csq_reduce_kernel(const float* __restrict__ part, float* __restrict__ csq) {
    int k = blockIdx.x * 256 + threadIdx.x;
    float s = 0.f;
#pragma unroll
    for (int p = 0; p < 16; ++p) s += part[p * KC + k];
    csq[k] = s;
}

// ---------- fallback-only csq ----------
__global__ void csq_kernel(const float* __restrict__ C, float* __restrict__ csq) {
    int k = blockIdx.x * blockDim.x + threadIdx.x;
    if (k < KC) {
        float s = 0.f;
        for (int d = 0; d < DIMS; ++d) {
            float v = C[d * KC + k];
            s = fmaf(v, v, s);
        }
        csq[k] = s;
    }
}

// ---------- main: fp16 MFMA GEMM, TRANSPOSED, FULL-K per block (no cross-block merge) ----------
// 1024 blocks, one per 128-point tile. Inner loop over 8 centroid tiles (cx); per cx the
// round-2-verified 128x128 BK=32 machinery runs (A = Ct cx-tile via global_load_lds,
// B = F fp32->fp16 reg path). C/D col = lane = POINT, row = reg = CENTROID: running
// in-register top-2 (bestA/bestB per nt) accumulates across all 8 cx tiles -> each block
// finishes its rows completely: plain out[] stores + LDS-compacted rescue list.
// Eliminates g1/g2 buffers, 2MB memset, 3.1M global atomics, flag_compact kernel.
__global__ __launch_bounds__(256, 4) void gemm_argmin_kernel(
    const float* __restrict__ F, const u16* __restrict__ Ct,
    const float* __restrict__ csq, float* __restrict__ out,
    u32* __restrict__ cnt, u32* __restrict__ list)
{
    __shared__ __align__(16) uint8_t smem[16384];
    __shared__ float csq_l[1024];
    __shared__ u32 lcnt, lbase;
    __shared__ u32 lrows[128];

    const int tid  = threadIdx.x;
    const int lane = tid & 63;
    const int wid  = tid >> 6;
    const int wm   = wid >> 1, wn = wid & 1;
    const int py   = (int)blockIdx.x;   // point tile 0..1023

    for (int i = tid; i < 1024; i += 256) csq_l[i] = csq[i];
    if (tid == 0) lcnt = 0;
    // (visibility of csq_l/lcnt guaranteed by the barriers inside the first kt iteration)

    // --- B staging (F/points): thread -> row = tid>>1 (0..127), h = tid&1 (16 floats)
    const int brow = tid >> 1, bh_ = tid & 1;
    const float* bF = F + (size_t)(py * 128 + brow) * DIMS + bh_ * 16;
    const int bxr = (brow >> 1) & 3;
    const unsigned bw0 = 8192u + (unsigned)(brow * 64 + (((bh_ * 2 + 0) ^ bxr) * 16));
    const unsigned bw1 = 8192u + (unsigned)(brow * 64 + (((bh_ * 2 + 1) ^ bxr) * 16));

    // --- A staging (Ct/centroids): 2 async calls/wave, each 16 rows x 64B
    const int c_st = (lane & 3) ^ ((lane >> 3) & 3);
    const u16* aBase0 = Ct + (size_t)(wid * 32 + (lane >> 2)) * DIMS + c_st * 8;
    const unsigned aw = (unsigned)(wid * 32) * 64;   // + lane*16 implied

    // --- fragment read offsets (identical layout both operands) ---
    const int kh = lane >> 5;
    const int cl = lane & 31;
    const int xr = (cl >> 1) & 3;
    const unsigned mb = (unsigned)cl * 64;
    const unsigned offs0 = mb + (unsigned)(((0 + kh) ^ xr) * 16);   // s=0: q=kh
    const unsigned offs1 = mb + (unsigned)(((2 + kh) ^ xr) * 16);   // s=1: q=2+kh

    // running top-2 per nt (each lane owns 2 points: wn*64 + nt*32 + cl)
    u64 bestA[2] = {~0ull, ~0ull};
    u64 bestB[2] = {~0ull, ~0ull};

    for (int cx = 0; cx < 8; ++cx) {
        const u16* aBase = aBase0 + (size_t)(cx * 128) * DIMS;

        f32x16 acc[2][2];
#pragma unroll
        for (int i = 0; i < 2; ++i)
#pragma unroll
            for (int j = 0; j < 2; ++j)
#pragma unroll
                for (int e = 0; e < 16; ++e) acc[i][j][e] = 0.f;

        for (int kt = 0; kt < DIMS / 32; ++kt) {
            const int k0 = kt * 32;
            // B global loads early (regs only; re-read per cx from L2/L3)
            float4 f0 = *(const float4*)(bF + k0);
            float4 f1 = *(const float4*)(bF + k0 + 4);
            float4 f2 = *(const float4*)(bF + k0 + 8);
            float4 f3 = *(const float4*)(bF + k0 + 12);

            __syncthreads();   // prev iter frag reads done
            // A: 2 async 16B-per-lane loads (16 centroid rows each)
            async_load16(aBase + k0,             smem + aw);
            async_load16(aBase + 16 * DIMS + k0, smem + aw + 1024);
            // B: convert + swizzled store
            {
                float v[16] = {f0.x, f0.y, f0.z, f0.w, f1.x, f1.y, f1.z, f1.w,
                               f2.x, f2.y, f2.z, f2.w, f3.x, f3.y, f3.z, f3.w};
                f16x8 h0, h1;
#pragma unroll
                for (int i = 0; i < 8; ++i) h0[i] = (f16)v[i];
#pragma unroll
                for (int i = 0; i < 8; ++i) h1[i] = (f16)v[8 + i];
                *(f16x8*)(smem + bw0) = h0;
                *(f16x8*)(smem + bw1) = h1;
            }
            __syncthreads();   // stage visible (drains vmcnt)

#pragma unroll
            for (int s = 0; s < 2; ++s) {
                const unsigned off = s ? offs1 : offs0;
                f16x8 a[2], b[2];
#pragma unroll
                for (int mt = 0; mt < 2; ++mt)
                    a[mt] = *(const f16x8*)(smem + wm * 4096 + mt * 2048 + off);
#pragma unroll
                for (int nt = 0; nt < 2; ++nt)
                    b[nt] = *(const f16x8*)(smem + 8192 + wn * 4096 + nt * 2048 + off);
#pragma unroll
                for (int mt = 0; mt < 2; ++mt)
#pragma unroll
                    for (int nt = 0; nt < 2; ++nt)
                        acc[mt][nt] = __builtin_amdgcn_mfma_f32_32x32x16_f16(a[mt], b[nt], acc[mt][nt], 0, 0, 0);
            }
        }

        // fold this cx tile into the running top-2 (registers + LDS-broadcast csq reads)
#pragma unroll
        for (int nt = 0; nt < 2; ++nt)
#pragma unroll
            for (int mt = 0; mt < 2; ++mt)
#pragma unroll
                for (int reg = 0; reg < 16; ++reg) {
                    const int rl = wm * 64 + mt * 32 + (reg & 3) + 8 * (reg >> 2) + 4 * kh;
                    const float d = fmaf(-2.0f, acc[mt][nt][reg], csq_l[cx * 128 + rl]);
                    const u64 key = ((u64)f2o(d) << 32) | (u32)(cx * 128 + rl);
                    const u64 t = umin64(bestA[nt], key);    // branchless top-2 insert
                    bestB[nt] = umin64(bestB[nt], umax64(bestA[nt], key));
                    bestA[nt] = t;
                }
    }

    __syncthreads();           // all frag reads done -> smem reusable as tbl
    u64* tbl = (u64*)smem;     // [128 points][wm:2][top2:2] = 4 KB

#pragma unroll
    for (int nt = 0; nt < 2; ++nt) {
        const u64 a = bestA[nt], b = bestB[nt];
        const u64 oa = __shfl_xor(a, 32, 64);    // merge kh halves (same point)
        const u64 ob = __shfl_xor(b, 32, 64);
        const u64 lo = umin64(a, oa);
        const u64 bb = umin64(umax64(a, oa), umin64(b, ob));
        if (kh == 0) {
            const int p = wn * 64 + nt * 32 + cl;
            tbl[(p * 2 + wm) * 2 + 0] = lo;
            tbl[(p * 2 + wm) * 2 + 1] = bb;
        }
    }
    __syncthreads();

    if (tid < 128) {
        const u64 a0 = tbl[tid * 4 + 0], b0 = tbl[tid * 4 + 1];
        const u64 a1 = tbl[tid * 4 + 2], b1 = tbl[tid * 4 + 3];
        const u64 m1 = umin64(a0, a1);
        const u64 m2 = umin64(umax64(a0, a1), umin64(b0, b1));
        const int row = py * 128 + tid;
        const float d1 = o2f((u32)(m1 >> 32));
        const float d2 = o2f((u32)(m2 >> 32));
        if (d2 - d1 > MARGIN) {
            out[row] = (float)(u32)(m1 & 1023u);     // safe: final answer, plain store
        } else {
            u32 li = atomicAdd(&lcnt, 1u);           // LDS atomic
            lrows[li] = (u32)row;
        }
    }
    __syncthreads();
    if (tid == 0 && lcnt > 0) lbase = atomicAdd(cnt, lcnt);   // 1 global atomic / block
    __syncthreads();
    if (tid < lcnt) list[lbase + tid] = lrows[tid];
}

// ---------- phase B: exact fp32 argmin for flagged rows (work-stealing, 4 rows/batch) ----------
__global__ __launch_bounds__(256) void rescue2_kernel(
    const float* __restrict__ F, const float* __restrict__ C,
    const float* __restrict__ csq, const u32* __restrict__ cnt,
    const u32* __restrict__ list, u32* __restrict__ wptr, float* __restrict__ out)
{
    __shared__ float xs[4][512];
    __shared__ u64 wavemin[4][4];
    __shared__ int rows_s[4];

    const int tid = threadIdx.x;
    const int lane = tid & 63;
    const int wid = tid >> 6;
    const u32 n = cnt[0];

    for (;;) {
        __syncthreads();
        u32 base;
        if (tid == 0) {
            base = atomicAdd(wptr, 4u);
            rows_s[0] = (int)base;
        }
        __syncthreads();
        base = (u32)rows_s[0];
        if (base >= n) break;

        int rows[4];
#pragma unroll
        for (int j = 0; j < 4; ++j) {
            u32 idx = base + j;
            rows[j] = (int)list[idx < n ? idx : (n - 1)];
        }
#pragma unroll
        for (int j = 0; j < 4; ++j) {
            if (tid < 128)
                *(float4*)&xs[j][tid * 4] = *(const float4*)&F[(size_t)rows[j] * DIMS + tid * 4];
        }
        __syncthreads();

        float dot[4][4];
#pragma unroll
        for (int j = 0; j < 4; ++j)
#pragma unroll
            for (int q = 0; q < 4; ++q) dot[j][q] = 0.f;

#pragma unroll 4
        for (int d = 0; d < DIMS; ++d) {
            float cv[4];
#pragma unroll
            for (int q = 0; q < 4; ++q) cv[q] = C[d * KC + tid + 256 * q];
            float xv[4];
#pragma unroll
            for (int j = 0; j < 4; ++j) xv[j] = xs[j][d];
#pragma unroll
            for (int j = 0; j < 4; ++j)
#pragma unroll
                for (int q = 0; q < 4; ++q)
                    dot[j][q] = fmaf(xv[j], cv[q], dot[j][q]);
        }

#pragma unroll
        for (int j = 0; j < 4; ++j) {
            u64 best = ~0ull;
#pragma unroll
            for (int q = 0; q < 4; ++q) {
                const int k = tid + 256 * q;
                const float dist = csq[k] - 2.0f * dot[j][q];
                best = umin64(best, ((u64)f2o(dist) << 32) | (u32)k);
            }
#pragma unroll
            for (int off = 32; off > 0; off >>= 1)
                best = umin64(best, __shfl_xor(best, off, 64));
            if (lane == 0) wavemin[j][wid] = best;
        }
        __syncthreads();
        if (tid < 4) {
            const u32 idx = base + tid;
            if (idx < n) {
                u64 b = umin64(umin64(wavemin[tid][0], wavemin[tid][1]),
                               umin64(wavemin[tid][2], wavemin[tid][3]));
                out[list[idx]] = (float)(u32)(b & 0xFFFFFFFFull);
            }
        }
    }
}

// ================= fallback (fp32 vector path, used only if ws too small) =================
__global__ __launch_bounds__(256, 3) void assign_kernel_fp32(
    const float* __restrict__ F, const float* __restrict__ C,
    const float* __restrict__ csq, float* __restrict__ out)
{
    __shared__ float At[32][68];
    __shared__ float Bs[32 * 256];
    __shared__ u64 best_row[64];

    const int tid = threadIdx.x;
    const int tx = tid & 31;
    const int ty = tid >> 5;
    const int n0 = blockIdx.x * 64;

    if (tid < 64) best_row[tid] = ~0ull;

    u64 best[8];
#pragma unroll
    for (int r = 0; r < 8; ++r) best[r] = ~0ull;

    const int arow = tid >> 3;
    const int ac4  = tid & 7;
    const float* Atp = &At[0][ty * 8];
    const float* Bsp = &Bs[tx * 4];

    for (int kt = 0; kt < 4; ++kt) {
        float acc[8][8];
#pragma unroll
        for (int r = 0; r < 8; ++r)
#pragma unroll
            for (int j = 0; j < 8; ++j) acc[r][j] = 0.f;

        for (int dt = 0; dt < DIMS / 32; ++dt) {
            __syncthreads();
#pragma unroll
            for (int i = 0; i < 2; ++i) {
                int row = arow + 32 * i;
                float4 av = *(const float4*)&F[(long)(n0 + row) * DIMS + dt * 32 + ac4 * 4];
                At[ac4 * 4 + 0][row] = av.x;
                At[ac4 * 4 + 1][row] = av.y;
                At[ac4 * 4 + 2][row] = av.z;
                At[ac4 * 4 + 3][row] = av.w;
            }
#pragma unroll
            for (int i = 0; i < 8; ++i) {
                int idx = tid + 256 * i;
                int d  = idx >> 6;
                int c4 = idx & 63;
                float4 bv = *(const float4*)&C[(long)(dt * 32 + d) * KC + kt * 256 + c4 * 4];
                *(float4*)&Bs[d * 256 + c4 * 4] = bv;
            }
            __syncthreads();

#pragma unroll 8
            for (int dd = 0; dd < 32; ++dd) {
                float4 a0 = *(const float4*)(Atp + dd * 68);
                float4 a1 = *(const float4*)(Atp + dd * 68 + 4);
                float4 b0 = *(const float4*)(Bsp + dd * 256);
                float4 b1 = *(const float4*)(Bsp + dd * 256 + 128);
                float a[8] = {a0.x, a0.y, a0.z, a0.w, a1.x, a1.y, a1.z, a1.w};
                float bb[8] = {b0.x, b0.y, b0.z, b0.w, b1.x, b1.y, b1.z, b1.w};
#pragma unroll
                for (int r = 0; r < 8; ++r)
#pragma unroll
                    for (int j = 0; j < 8; ++j)
                        acc[r][j] = fmaf(a[r], bb[j], acc[r][j]);
            }
        }

        float4 cs0 = *(const float4*)&csq[kt * 256 + tx * 4];
        float4 cs1 = *(const float4*)&csq[kt * 256 + 128 + tx * 4];
        float cs[8] = {cs0.x, cs0.y, cs0.z, cs0.w, cs1.x, cs1.y, cs1.z, cs1.w};
#pragma unroll
        for (int j = 0; j < 8; ++j) {
            int k = kt * 256 + ((j < 4) ? (tx * 4 + j) : (128 + tx * 4 + (j - 4)));
#pragma unroll
            for (int r = 0; r < 8; ++r) {
                float val = cs[j] - 2.0f * acc[r][j];
                u64 key = ((u64)f2o(val) << 32) | (u64)(unsigned)k;
                if (key < best[r]) best[r] = key;
            }
        }
    }

#pragma unroll
    for (int r = 0; r < 8; ++r)
        atomicMin(&best_row[ty * 8 + r], best[r]);
    __syncthreads();

    if (tid < 64)
        out[n0 + tid] = (float)(unsigned)(best_row[tid] & 0xFFFFFFFFull);
}

// ================= launch =================
extern "C" void kernel_launch(void* const* d_in, const int* in_sizes, int n_in,
                              void* d_out, int out_size, void* d_ws, size_t ws_size,
                              hipStream_t stream) {
    const float* F = (const float*)d_in[0];   // [131072, 512]
    const float* C = (const float*)d_in[1];   // [512, 1024]
    float* out = (float*)d_out;               // [131072]
    char* ws = (char*)d_ws;

    if (ws_size < WS_NEEDED) {
        float* csq = (float*)d_ws;
        csq_kernel<<<KC / 256, 256, 0, stream>>>(C, csq);
        assign_kernel_fp32<<<NPTS / 64, 256, 0, stream>>>(F, C, csq, out);
        return;
    }

    u16* Ct = (u16*)(ws + CT_OFF);
    float* csq  = (float*)(ws + CSQ_OFF);
    float* csqp = (float*)(ws + CSQP_OFF);
    u32* cnt  = (u32*)(ws + CNT_OFF);
    u32* list = (u32*)(ws + LIST_OFF);

    hipMemsetAsync(cnt, 0, 8, stream);        // cnt[0] = list count, cnt[1] = rescue wptr
    split_c_kernel<<<dim3(KC / 32, DIMS / 32), 256, 0, stream>>>(C, Ct, csqp);
    csq_reduce_kernel<<<KC / 256, 256, 0, stream>>>(csqp, csq);
    gemm_argmin_kernel<<<NPTS / 128, 256, 0, stream>>>(F, Ct, csq, out, cnt, list);
    rescue2_kernel<<<1024, 256, 0, stream>>>(F, C, csq, cnt, list, cnt + 1, out);
}

// Round 4
// 691.239 us; speedup vs baseline: 1.3734x; 1.0546x over previous
//
#include <hip/hip_runtime.h>
#include <hip/hip_bf16.h>

#define NPTS 131072
#define DIMS 512
#define KC   1024

typedef _Float16 f16;
using f16x8  = __attribute__((ext_vector_type(8))) _Float16;
using f32x16 = __attribute__((ext_vector_type(16))) float;
typedef unsigned short u16;
typedef unsigned int u32;
typedef unsigned long long u64;

// ---- workspace layout (bytes) ----
#define CT_OFF     0ull            // Ct [1024][512] fp16 = 1 MB
#define CSQ_OFF    1048576ull      // 4 KB
#define CSQP_OFF   1052672ull      // 16*1024 floats = 64 KB
#define CNT_OFF    1118208ull      // 256 B
#define LIST_OFF   1118464ull      // 512 KB
#define WS_NEEDED  1642752ull

#define MARGIN 0.2f

// ---------- helpers ----------
__device__ __forceinline__ u32 f2o(float f) {
    u32 u = __float_as_uint(f);
    return (u & 0x80000000u) ? ~u : (u | 0x80000000u);
}
__device__ __forceinline__ float o2f(u32 o) {
    u32 u = (o & 0x80000000u) ? (o & 0x7FFFFFFFu) : ~o;
    return __uint_as_float(u);
}
__device__ __forceinline__ u64 umin64(u64 a, u64 b) { return a < b ? a : b; }
__device__ __forceinline__ u64 umax64(u64 a, u64 b) { return a > b ? a : b; }

// global -> LDS direct (16B per lane). LDS dest is wave-uniform base + lane*16.
__device__ __forceinline__ void async_load16(const void* g, const void* l) {
    auto gp = reinterpret_cast<__attribute__((address_space(1))) void*>(
        reinterpret_cast<uintptr_t>(g));
    auto lp = reinterpret_cast<__attribute__((address_space(3))) void*>(
        (unsigned int)reinterpret_cast<uintptr_t>(l));
    __builtin_amdgcn_global_load_lds(gp, lp, 16, 0, 0);
}

// ---------- prepass: transpose C [512][1024] -> Ct [1024][512] fp16 + csq partials ----------
__global__ void split_c_kernel(const float* __restrict__ C,
                               u16* __restrict__ ct, float* __restrict__ csq_part) {
    __shared__ float t[32][33];
    int bn = blockIdx.x, bd = blockIdx.y;
    int tx = threadIdx.x & 31, ty = threadIdx.x >> 5;
#pragma unroll
    for (int r = 0; r < 32; r += 8)
        t[ty + r][tx] = C[(size_t)(bd * 32 + ty + r) * KC + bn * 32 + tx];
    __syncthreads();
#pragma unroll
    for (int r = 0; r < 32; r += 8) {
        int n = bn * 32 + ty + r, d = bd * 32 + tx;
        float v = t[tx][ty + r];
        f16 h = (f16)v;
        ct[(size_t)n * DIMS + d] = *reinterpret_cast<u16*>(&h);
        float sq = v * v;
#pragma unroll
        for (int m = 1; m < 32; m <<= 1)
            sq += __shfl_xor(sq, m, 64);
        if (tx == 0) csq_part[bd * KC + n] = sq;
    }
}

// ---------- csq: deterministic 16-part reduce ----------
__global__ void csq_reduce_kernel(const float* __restrict__ part, float* __restrict__ csq) {
    int k = blockIdx.x * 256 + threadIdx.x;
    float s = 0.f;
#pragma unroll
    for (int p = 0; p < 16; ++p) s += part[p * KC + k];
    csq[k] = s;
}

// ---------- fallback-only csq ----------
__global__ void csq_kernel(const float* __restrict__ C, float* __restrict__ csq) {
    int k = blockIdx.x * blockDim.x + threadIdx.x;
    if (k < KC) {
        float s = 0.f;
        for (int d = 0; d < DIMS; ++d) {
            float v = C[d * KC + k];
            s = fmaf(v, v, s);
        }
        csq[k] = s;
    }
}

// ---------- main: fp16 MFMA GEMM, TRANSPOSED, B-IN-REGISTERS (F read exactly once) ----------
// 1024 blocks x 512 threads (8 waves: wm{0,1} x wn{0..3}). Per block: 128 points x 1024 centroids.
// B (points): each lane holds HALF of one point row in regs as fp16 (b_reg[32] f16x8 = 128 VGPR):
//   MFMA lane (cl,kh) only consumes dims kt*32+(2s+kh)*8..+8 of point row wn*32+cl.
//   -> F is read ONCE (256 KB/block), converted once; no per-cx re-read (was 674 MB fetch).
// A (centroids): 8 KB kt-tile via global_load_lds, double-buffered; stage(t+1) issued at TOP
//   of iteration t, single __syncthreads at bottom -> stage latency hides under ds_read+MFMA.
// C/D: col = lane = point, row = reg = centroid -> running in-register top-2 across all cx.
__global__ __launch_bounds__(512, 2) void gemm_argmin_kernel(
    const float* __restrict__ F, const u16* __restrict__ Ct,
    const float* __restrict__ csq, float* __restrict__ out,
    u32* __restrict__ cnt, u32* __restrict__ list)
{
    __shared__ __align__(16) uint8_t smem[16384];   // A double buffer: 2 x 8 KB
    __shared__ float csq_l[1024];
    __shared__ u32 lcnt, lbase;
    __shared__ u32 lrows[128];

    const int tid  = threadIdx.x;
    const int lane = tid & 63;
    const int wid  = tid >> 6;        // 0..7
    const int wm   = wid >> 2;        // centroid half (0..1)
    const int wn   = wid & 3;         // point quarter (0..3)
    const int py   = (int)blockIdx.x; // point tile 0..1023

    const int kh = lane >> 5;
    const int cl = lane & 31;

    for (int i = tid; i < 1024; i += 512) csq_l[i] = csq[i];
    if (tid == 0) lcnt = 0;

    // ---- B: load this lane's point half-row once, convert to fp16 in regs ----
    const float* fRow = F + (size_t)(py * 128 + wn * 32 + cl) * DIMS + kh * 8;
    f16x8 b_reg[32];   // [kt*2+s]; all indices compile-time (loops fully unrolled)
#pragma unroll
    for (int kt = 0; kt < 16; ++kt)
#pragma unroll
        for (int s = 0; s < 2; ++s) {
            float4 x0 = *(const float4*)(fRow + kt * 32 + s * 16);
            float4 x1 = *(const float4*)(fRow + kt * 32 + s * 16 + 4);
            f16x8 h;
            h[0] = (f16)x0.x; h[1] = (f16)x0.y; h[2] = (f16)x0.z; h[3] = (f16)x0.w;
            h[4] = (f16)x1.x; h[5] = (f16)x1.y; h[6] = (f16)x1.z; h[7] = (f16)x1.w;
            b_reg[kt * 2 + s] = h;
        }

    // ---- A staging: 1 async call/wave/kt = 16 rows x 64B; source pre-swizzled ----
    const int lr   = lane >> 2;                        // local row 0..15
    const int c_st = (lane & 3) ^ ((lane >> 3) & 3);   // (lane>>3)&3 == (lr>>1)&3
    const u16* aStage = Ct + (size_t)(wid * 16 + lr) * DIMS + c_st * 8;
    const unsigned awdst = (unsigned)(wid * 1024);     // + lane*16 implied

    // ---- fragment read offsets (XOR-swizzled chunks) ----
    const int xr = (cl >> 1) & 3;
    const unsigned mbase = (unsigned)cl * 64;
    const unsigned offs[2] = { mbase + (unsigned)(((0 + kh) ^ xr) * 16),    // s=0: q=kh
                               mbase + (unsigned)(((2 + kh) ^ xr) * 16) };  // s=1: q=2+kh

    u64 bestA = ~0ull, bestB = ~0ull;
    f32x16 acc[2];

    // prologue: stage (cx=0,kt=0) into buf0; barrier drains it (+ csq_l/lcnt visible)
    async_load16(aStage, smem + awdst);
    __syncthreads();

    for (int cx = 0; cx < 8; ++cx) {
        const size_t cxoff = (size_t)cx * (128 * DIMS);
#pragma unroll
        for (int e = 0; e < 16; ++e) { acc[0][e] = 0.f; acc[1][e] = 0.f; }

#pragma unroll
        for (int kt = 0; kt < 16; ++kt) {
            // stage NEXT kt-tile into the other buffer (latency hides under this kt's compute;
            // safe: the other buffer's readers finished before the previous barrier)
            if (!(cx == 7 && kt == 15)) {
                const size_t noff = (kt == 15) ? (cxoff + (size_t)(128 * DIMS))
                                               : (cxoff + (size_t)((kt + 1) * 32));
                async_load16(aStage + noff,
                             smem + (((kt + 1) & 1) ? 8192u : 0u) + awdst);
            }
            const unsigned buf = (kt & 1) ? 8192u : 0u;
#pragma unroll
            for (int s = 0; s < 2; ++s) {
                f16x8 a0 = *(const f16x8*)(smem + buf + wm * 4096 + 0 * 2048 + offs[s]);
                f16x8 a1 = *(const f16x8*)(smem + buf + wm * 4096 + 1 * 2048 + offs[s]);
                acc[0] = __builtin_amdgcn_mfma_f32_32x32x16_f16(a0, b_reg[kt * 2 + s], acc[0], 0, 0, 0);
                acc[1] = __builtin_amdgcn_mfma_f32_32x32x16_f16(a1, b_reg[kt * 2 + s], acc[1], 0, 0, 0);
            }
            __syncthreads();   // drains next-tile stage; one barrier per kt
        }

        // fold this cx tile into the running top-2 (regs + csq_l broadcast reads)
#pragma unroll
        for (int mt = 0; mt < 2; ++mt)
#pragma unroll
            for (int reg = 0; reg < 16; ++reg) {
                const int rl = wm * 64 + mt * 32 + (reg & 3) + 8 * (reg >> 2) + 4 * kh;
                const float d = fmaf(-2.0f, acc[mt][reg], csq_l[cx * 128 + rl]);
                const u64 key = ((u64)f2o(d) << 32) | (u32)(cx * 128 + rl);
                const u64 t = umin64(bestA, key);    // branchless top-2 insert
                bestB = umin64(bestB, umax64(bestA, key));
                bestA = t;
            }
    }

    // ---- merge kh halves (lane^32 = same point, other centroid rows) ----
    {
        const u64 oa = __shfl_xor(bestA, 32, 64);
        const u64 ob = __shfl_xor(bestB, 32, 64);
        const u64 lo = umin64(bestA, oa);
        const u64 bb = umin64(umax64(bestA, oa), umin64(bestB, ob));
        u64* tbl = (u64*)smem;   // [128 points][wm:2][top2:2] = 4 KB (A buffers dead)
        if (kh == 0) {
            const int p = wn * 32 + cl;
            tbl[(p * 2 + wm) * 2 + 0] = lo;
            tbl[(p * 2 + wm) * 2 + 1] = bb;
        }
    }
    __syncthreads();

    if (tid < 128) {
        u64* tbl = (u64*)smem;
        const u64 a0 = tbl[tid * 4 + 0], b0 = tbl[tid * 4 + 1];
        const u64 a1 = tbl[tid * 4 + 2], b1 = tbl[tid * 4 + 3];
        const u64 m1 = umin64(a0, a1);
        const u64 m2 = umin64(umax64(a0, a1), umin64(b0, b1));
        const int row = py * 128 + tid;
        const float d1 = o2f((u32)(m1 >> 32));
        const float d2 = o2f((u32)(m2 >> 32));
        if (d2 - d1 > MARGIN) {
            out[row] = (float)(u32)(m1 & 1023u);     // final answer, plain store
        } else {
            u32 li = atomicAdd(&lcnt, 1u);           // LDS atomic
            lrows[li] = (u32)row;
        }
    }
    __syncthreads();
    if (tid == 0 && lcnt > 0) lbase = atomicAdd(cnt, lcnt);   // 1 global atomic / block
    __syncthreads();
    if (tid < lcnt) list[lbase + tid] = lrows[tid];
}

// ---------- phase B: exact fp32 argmin for flagged rows (work-stealing, 4 rows/batch) ----------
__global__ __launch_bounds__(256) void rescue2_kernel(
    const float* __restrict__ F, const float* __restrict__ C,
    const float* __restrict__ csq, const u32* __restrict__ cnt,
    const u32* __restrict__ list, u32* __restrict__ wptr, float* __restrict__ out)
{
    __shared__ float xs[4][512];
    __shared__ u64 wavemin[4][4];
    __shared__ int rows_s[4];

    const int tid = threadIdx.x;
    const int lane = tid & 63;
    const int wid = tid >> 6;
    const u32 n = cnt[0];

    for (;;) {
        __syncthreads();
        u32 base;
        if (tid == 0) {
            base = atomicAdd(wptr, 4u);
            rows_s[0] = (int)base;
        }
        __syncthreads();
        base = (u32)rows_s[0];
        if (base >= n) break;

        int rows[4];
#pragma unroll
        for (int j = 0; j < 4; ++j) {
            u32 idx = base + j;
            rows[j] = (int)list[idx < n ? idx : (n - 1)];
        }
#pragma unroll
        for (int j = 0; j < 4; ++j) {
            if (tid < 128)
                *(float4*)&xs[j][tid * 4] = *(const float4*)&F[(size_t)rows[j] * DIMS + tid * 4];
        }
        __syncthreads();

        float dot[4][4];
#pragma unroll
        for (int j = 0; j < 4; ++j)
#pragma unroll
            for (int q = 0; q < 4; ++q) dot[j][q] = 0.f;

#pragma unroll 4
        for (int d = 0; d < DIMS; ++d) {
            float cv[4];
#pragma unroll
            for (int q = 0; q < 4; ++q) cv[q] = C[d * KC + tid + 256 * q];
            float xv[4];
#pragma unroll
            for (int j = 0; j < 4; ++j) xv[j] = xs[j][d];
#pragma unroll
            for (int j = 0; j < 4; ++j)
#pragma unroll
                for (int q = 0; q < 4; ++q)
                    dot[j][q] = fmaf(xv[j], cv[q], dot[j][q]);
        }

#pragma unroll
        for (int j = 0; j < 4; ++j) {
            u64 best = ~0ull;
#pragma unroll
            for (int q = 0; q < 4; ++q) {
                const int k = tid + 256 * q;
                const float dist = csq[k] - 2.0f * dot[j][q];
                best = umin64(best, ((u64)f2o(dist) << 32) | (u32)k);
            }
#pragma unroll
            for (int off = 32; off > 0; off >>= 1)
                best = umin64(best, __shfl_xor(best, off, 64));
            if (lane == 0) wavemin[j][wid] = best;
        }
        __syncthreads();
        if (tid < 4) {
            const u32 idx = base + tid;
            if (idx < n) {
                u64 b = umin64(umin64(wavemin[tid][0], wavemin[tid][1]),
                               umin64(wavemin[tid][2], wavemin[tid][3]));
                out[list[idx]] = (float)(u32)(b & 0xFFFFFFFFull);
            }
        }
    }
}

// ================= fallback (fp32 vector path, used only if ws too small) =================
__global__ __launch_bounds__(256, 3) void assign_kernel_fp32(
    const float* __restrict__ F, const float* __restrict__ C,
    const float* __restrict__ csq, float* __restrict__ out)
{
    __shared__ float At[32][68];
    __shared__ float Bs[32 * 256];
    __shared__ u64 best_row[64];

    const int tid = threadIdx.x;
    const int tx = tid & 31;
    const int ty = tid >> 5;
    const int n0 = blockIdx.x * 64;

    if (tid < 64) best_row[tid] = ~0ull;

    u64 best[8];
#pragma unroll
    for (int r = 0; r < 8; ++r) best[r] = ~0ull;

    const int arow = tid >> 3;
    const int ac4  = tid & 7;
    const float* Atp = &At[0][ty * 8];
    const float* Bsp = &Bs[tx * 4];

    for (int kt = 0; kt < 4; ++kt) {
        float acc[8][8];
#pragma unroll
        for (int r = 0; r < 8; ++r)
#pragma unroll
            for (int j = 0; j < 8; ++j) acc[r][j] = 0.f;

        for (int dt = 0; dt < DIMS / 32; ++dt) {
            __syncthreads();
#pragma unroll
            for (int i = 0; i < 2; ++i) {
                int row = arow + 32 * i;
                float4 av = *(const float4*)&F[(long)(n0 + row) * DIMS + dt * 32 + ac4 * 4];
                At[ac4 * 4 + 0][row] = av.x;
                At[ac4 * 4 + 1][row] = av.y;
                At[ac4 * 4 + 2][row] = av.z;
                At[ac4 * 4 + 3][row] = av.w;
            }
#pragma unroll
            for (int i = 0; i < 8; ++i) {
                int idx = tid + 256 * i;
                int d  = idx >> 6;
                int c4 = idx & 63;
                float4 bv = *(const float4*)&C[(long)(dt * 32 + d) * KC + kt * 256 + c4 * 4];
                *(float4*)&Bs[d * 256 + c4 * 4] = bv;
            }
            __syncthreads();

#pragma unroll 8
            for (int dd = 0; dd < 32; ++dd) {
                float4 a0 = *(const float4*)(Atp + dd * 68);
                float4 a1 = *(const float4*)(Atp + dd * 68 + 4);
                float4 b0 = *(const float4*)(Bsp + dd * 256);
                float4 b1 = *(const float4*)(Bsp + dd * 256 + 128);
                float a[8] = {a0.x, a0.y, a0.z, a0.w, a1.x, a1.y, a1.z, a1.w};
                float bb[8] = {b0.x, b0.y, b0.z, b0.w, b1.x, b1.y, b1.z, b1.w};
#pragma unroll
                for (int r = 0; r < 8; ++r)
#pragma unroll
                    for (int j = 0; j < 8; ++j)
                        acc[r][j] = fmaf(a[r], bb[j], acc[r][j]);
            }
        }

        float4 cs0 = *(const float4*)&csq[kt * 256 + tx * 4];
        float4 cs1 = *(const float4*)&csq[kt * 256 + 128 + tx * 4];
        float cs[8] = {cs0.x, cs0.y, cs0.z, cs0.w, cs1.x, cs1.y, cs1.z, cs1.w};
#pragma unroll
        for (int j = 0; j < 8; ++j) {
            int k = kt * 256 + ((j < 4) ? (tx * 4 + j) : (128 + tx * 4 + (j - 4)));
#pragma unroll
            for (int r = 0; r < 8; ++r) {
                float val = cs[j] - 2.0f * acc[r][j];
                u64 key = ((u64)f2o(val) << 32) | (u64)(unsigned)k;
                if (key < best[r]) best[r] = key;
            }
        }
    }

#pragma unroll
    for (int r = 0; r < 8; ++r)
        atomicMin(&best_row[ty * 8 + r], best[r]);
    __syncthreads();

    if (tid < 64)
        out[n0 + tid] = (float)(unsigned)(best_row[tid] & 0xFFFFFFFFull);
}

// ================= launch =================
extern "C" void kernel_launch(void* const* d_in, const int* in_sizes, int n_in,
                              void* d_out, int out_size, void* d_ws, size_t ws_size,
                              hipStream_t stream) {
    const float* F = (const float*)d_in[0];   // [131072, 512]
    const float* C = (const float*)d_in[1];   // [512, 1024]
    float* out = (float*)d_out;               // [131072]
    char* ws = (char*)d_ws;

    if (ws_size < WS_NEEDED) {
        float* csq = (float*)d_ws;
        csq_kernel<<<KC / 256, 256, 0, stream>>>(C, csq);
        assign_kernel_fp32<<<NPTS / 64, 256, 0, stream>>>(F, C, csq, out);
        return;
    }

    u16* Ct = (u16*)(ws + CT_OFF);
    float* csq  = (float*)(ws + CSQ_OFF);
    float* csqp = (float*)(ws + CSQP_OFF);
    u32* cnt  = (u32*)(ws + CNT_OFF);
    u32* list = (u32*)(ws + LIST_OFF);

    hipMemsetAsync(cnt, 0, 8, stream);        // cnt[0] = list count, cnt[1] = rescue wptr
    split_c_kernel<<<dim3(KC / 32, DIMS / 32), 256, 0, stream>>>(C, Ct, csqp);
    csq_reduce_kernel<<<KC / 256, 256, 0, stream>>>(csqp, csq);
    gemm_argmin_kernel<<<NPTS / 128, 512, 0, stream>>>(F, Ct, csq, out, cnt, list);
    rescue2_kernel<<<1024, 256, 0, stream>>>(F, C, csq, cnt, list, cnt + 1, out);
}

// Round 5
// 683.956 us; speedup vs baseline: 1.3881x; 1.0106x over previous
//
#include <hip/hip_runtime.h>
#include <hip/hip_bf16.h>

#define NPTS 131072
#define DIMS 512
#define KC   1024

typedef _Float16 f16;
using f16x8  = __attribute__((ext_vector_type(8))) _Float16;
using f32x16 = __attribute__((ext_vector_type(16))) float;
typedef unsigned short u16;
typedef unsigned int u32;
typedef unsigned long long u64;

// ---- workspace layout (bytes) ----
#define CT_OFF     0ull            // Ct [1024][512] fp16 = 1 MB
#define CSQ_OFF    1048576ull      // 4 KB
#define CSQP_OFF   1052672ull      // 16*1024 floats = 64 KB
#define CNT_OFF    1118208ull      // 256 B
#define LIST_OFF   1118464ull      // 512 KB
#define WS_NEEDED  1642752ull

#define MARGIN 0.2f

// ---------- helpers ----------
__device__ __forceinline__ u32 f2o(float f) {
    u32 u = __float_as_uint(f);
    return (u & 0x80000000u) ? ~u : (u | 0x80000000u);
}
__device__ __forceinline__ float o2f(u32 o) {
    u32 u = (o & 0x80000000u) ? (o & 0x7FFFFFFFu) : ~o;
    return __uint_as_float(u);
}
__device__ __forceinline__ u64 umin64(u64 a, u64 b) { return a < b ? a : b; }
__device__ __forceinline__ u64 umax64(u64 a, u64 b) { return a > b ? a : b; }

// global -> LDS direct (16B per lane). LDS dest is wave-uniform base + lane*16.
__device__ __forceinline__ void async_load16(const void* g, const void* l) {
    auto gp = reinterpret_cast<__attribute__((address_space(1))) void*>(
        reinterpret_cast<uintptr_t>(g));
    auto lp = reinterpret_cast<__attribute__((address_space(3))) void*>(
        (unsigned int)reinterpret_cast<uintptr_t>(l));
    __builtin_amdgcn_global_load_lds(gp, lp, 16, 0, 0);
}

// ---------- prepass: transpose C [512][1024] -> Ct [1024][512] fp16 + csq partials ----------
__global__ void split_c_kernel(const float* __restrict__ C,
                               u16* __restrict__ ct, float* __restrict__ csq_part) {
    __shared__ float t[32][33];
    int bn = blockIdx.x, bd = blockIdx.y;
    int tx = threadIdx.x & 31, ty = threadIdx.x >> 5;
#pragma unroll
    for (int r = 0; r < 32; r += 8)
        t[ty + r][tx] = C[(size_t)(bd * 32 + ty + r) * KC + bn * 32 + tx];
    __syncthreads();
#pragma unroll
    for (int r = 0; r < 32; r += 8) {
        int n = bn * 32 + ty + r, d = bd * 32 + tx;
        float v = t[tx][ty + r];
        f16 h = (f16)v;
        ct[(size_t)n * DIMS + d] = *reinterpret_cast<u16*>(&h);
        float sq = v * v;
#pragma unroll
        for (int m = 1; m < 32; m <<= 1)
            sq += __shfl_xor(sq, m, 64);
        if (tx == 0) csq_part[bd * KC + n] = sq;
    }
}

// ---------- csq: deterministic 16-part reduce ----------
__global__ void csq_reduce_kernel(const float* __restrict__ part, float* __restrict__ csq) {
    int k = blockIdx.x * 256 + threadIdx.x;
    float s = 0.f;
#pragma unroll
    for (int p = 0; p < 16; ++p) s += part[p * KC + k];
    csq[k] = s;
}

// ---------- fallback-only csq ----------
__global__ void csq_kernel(const float* __restrict__ C, float* __restrict__ csq) {
    int k = blockIdx.x * blockDim.x + threadIdx.x;
    if (k < KC) {
        float s = 0.f;
        for (int d = 0; d < DIMS; ++d) {
            float v = C[d * KC + k];
            s = fmaf(v, v, s);
        }
        csq[k] = s;
    }
}

// ---------- main: fp16 MFMA GEMM, TRANSPOSED, B-in-regs, SUPER-TILE pipeline ----------
// 1024 blocks x 512 threads (8 waves: wm{0,1} x wn{0..3}). Per block: 128 points x 1024 centroids.
// B (points): each lane holds HALF of one point row in fp16 regs (b_reg[32] f16x8, 128 VGPR).
//   F read exactly once (256 MB total).
// A (centroids): SUPER-TILES of 8 kt (128 rows x 256 dims = 64 KB), double-buffered in
//   128 KB dynamic LDS. Stage of super s+1 (8 async ops/wave) issued at TOP of super s;
//   ONE __syncthreads per super (drains vmcnt) -> stage latency hides under 8 kt of
//   ds_read+MFMA (~1K cyc). 17 barriers/block instead of 129.
// Super s: cx = s>>1, dim half h = s&1. h is a compile-time unrolled loop so b_reg
// indices and buffer selects are static (no scratch).
// C/D: col = lane = point, row = reg = centroid -> running in-register top-2 across cx.
__global__ __launch_bounds__(512, 2) void gemm_argmin_kernel(
    const float* __restrict__ F, const u16* __restrict__ Ct,
    const float* __restrict__ csq, float* __restrict__ out,
    u32* __restrict__ cnt, u32* __restrict__ list)
{
    extern __shared__ __align__(16) uint8_t dsm[];   // 2 x 64 KB A super-buffers
    __shared__ float csq_l[1024];
    __shared__ u32 lcnt, lbase;
    __shared__ u32 lrows[128];

    const int tid  = threadIdx.x;
    const int lane = tid & 63;
    const int wid  = tid >> 6;        // 0..7
    const int wm   = wid >> 2;        // centroid half (0..1)
    const int wn   = wid & 3;         // point quarter (0..3)
    const int py   = (int)blockIdx.x; // point tile 0..1023

    const int kh = lane >> 5;
    const int cl = lane & 31;

    for (int i = tid; i < 1024; i += 512) csq_l[i] = csq[i];
    if (tid == 0) lcnt = 0;

    // ---- A staging geometry: per wave, 16 rows x 64B per kt-tile; source pre-swizzled ----
    const int lr   = lane >> 2;                        // local row 0..15
    const int c_st = (lane & 3) ^ ((lane >> 3) & 3);   // == (l&3) ^ ((lr>>1)&3)
    const u16* aStage = Ct + (size_t)(wid * 16 + lr) * DIMS + c_st * 8;
    const unsigned awdst = (unsigned)(wid * 1024);     // within kt-tile; + lane*16 implied

    // prologue: stage super 0 (cx=0, dims 0..255) into buffer 0 -> hides under b_reg HBM reads
#pragma unroll
    for (int k = 0; k < 8; ++k)
        async_load16(aStage + k * 32, dsm + k * 8192 + awdst);

    // ---- B: load this lane's point half-row once, convert to fp16 in regs ----
    const float* fRow = F + (size_t)(py * 128 + wn * 32 + cl) * DIMS + kh * 8;
    f16x8 b_reg[32];   // [abs_kt*2+s]; all indices compile-time
#pragma unroll
    for (int kt = 0; kt < 16; ++kt)
#pragma unroll
        for (int s = 0; s < 2; ++s) {
            float4 x0 = *(const float4*)(fRow + kt * 32 + s * 16);
            float4 x1 = *(const float4*)(fRow + kt * 32 + s * 16 + 4);
            f16x8 hv;
            hv[0] = (f16)x0.x; hv[1] = (f16)x0.y; hv[2] = (f16)x0.z; hv[3] = (f16)x0.w;
            hv[4] = (f16)x1.x; hv[5] = (f16)x1.y; hv[6] = (f16)x1.z; hv[7] = (f16)x1.w;
            b_reg[kt * 2 + s] = hv;
        }

    // ---- fragment read offsets (XOR-swizzled 16B chunks within row's 64B) ----
    const int xr = (cl >> 1) & 3;
    const unsigned mbase = (unsigned)cl * 64;
    const unsigned offs[2] = { mbase + (unsigned)(((0 + kh) ^ xr) * 16),    // s=0: q=kh
                               mbase + (unsigned)(((2 + kh) ^ xr) * 16) };  // s=1: q=2+kh

    u64 bestA = ~0ull, bestB = ~0ull;
    f32x16 acc[2];

    __syncthreads();   // drains stage(0) + b_reg; csq_l/lcnt visible

    for (int c = 0; c < 8; ++c) {
#pragma unroll
        for (int h = 0; h < 2; ++h) {              // h compile-time after unroll
            // --- stage NEXT super into the other buffer (consumed 2 supers ago -> free) ---
            if (!(c == 7 && h == 1)) {
                const size_t nbase = (h == 0) ? ((size_t)c * 65536 + 256)
                                              : ((size_t)(c + 1) * 65536);
#pragma unroll
                for (int k = 0; k < 8; ++k)
                    async_load16(aStage + nbase + k * 32,
                                 dsm + (h ^ 1) * 65536 + k * 8192 + awdst);
            }
            if (h == 0) {
#pragma unroll
                for (int e = 0; e < 16; ++e) { acc[0][e] = 0.f; acc[1][e] = 0.f; }
            }
            // --- compute current super from buffer h (staged last super, drained at barrier) ---
#pragma unroll
            for (int k = 0; k < 8; ++k) {
#pragma unroll
                for (int s = 0; s < 2; ++s) {
                    const uint8_t* tile = dsm + h * 65536 + k * 8192;
                    f16x8 a0 = *(const f16x8*)(tile + wm * 4096 + 0 * 2048 + offs[s]);
                    f16x8 a1 = *(const f16x8*)(tile + wm * 4096 + 1 * 2048 + offs[s]);
                    const f16x8 bv = b_reg[(h * 8 + k) * 2 + s];
                    acc[0] = __builtin_amdgcn_mfma_f32_32x32x16_f16(a0, bv, acc[0], 0, 0, 0);
                    acc[1] = __builtin_amdgcn_mfma_f32_32x32x16_f16(a1, bv, acc[1], 0, 0, 0);
                }
            }
            // --- fold cx tile into running top-2 (register-only) ---
            if (h == 1) {
#pragma unroll
                for (int mt = 0; mt < 2; ++mt)
#pragma unroll
                    for (int reg = 0; reg < 16; ++reg) {
                        const int rl = wm * 64 + mt * 32 + (reg & 3) + 8 * (reg >> 2) + 4 * kh;
                        const float d = fmaf(-2.0f, acc[mt][reg], csq_l[c * 128 + rl]);
                        const u64 key = ((u64)f2o(d) << 32) | (u32)(c * 128 + rl);
                        const u64 t = umin64(bestA, key);    // branchless top-2 insert
                        bestB = umin64(bestB, umax64(bestA, key));
                        bestA = t;
                    }
            }
            __syncthreads();   // drains my 8 stage ops; all waves done reading buffer h
        }
    }

    // ---- merge kh halves (lane^32 = same point, other centroid rows) ----
    {
        const u64 oa = __shfl_xor(bestA, 32, 64);
        const u64 ob = __shfl_xor(bestB, 32, 64);
        const u64 lo = umin64(bestA, oa);
        const u64 bb = umin64(umax64(bestA, oa), umin64(bestB, ob));
        u64* tbl = (u64*)dsm;   // [128 points][wm:2][top2:2] = 4 KB (buffers dead)
        if (kh == 0) {
            const int p = wn * 32 + cl;
            tbl[(p * 2 + wm) * 2 + 0] = lo;
            tbl[(p * 2 + wm) * 2 + 1] = bb;
        }
    }
    __syncthreads();

    if (tid < 128) {
        u64* tbl = (u64*)dsm;
        const u64 a0 = tbl[tid * 4 + 0], b0 = tbl[tid * 4 + 1];
        const u64 a1 = tbl[tid * 4 + 2], b1 = tbl[tid * 4 + 3];
        const u64 m1 = umin64(a0, a1);
        const u64 m2 = umin64(umax64(a0, a1), umin64(b0, b1));
        const int row = py * 128 + tid;
        const float d1 = o2f((u32)(m1 >> 32));
        const float d2 = o2f((u32)(m2 >> 32));
        if (d2 - d1 > MARGIN) {
            out[row] = (float)(u32)(m1 & 1023u);     // final answer, plain store
        } else {
            u32 li = atomicAdd(&lcnt, 1u);           // LDS atomic
            lrows[li] = (u32)row;
        }
    }
    __syncthreads();
    if (tid == 0 && lcnt > 0) lbase = atomicAdd(cnt, lcnt);   // 1 global atomic / block
    __syncthreads();
    if (tid < lcnt) list[lbase + tid] = lrows[tid];
}

// ---------- phase B: exact fp32 argmin for flagged rows (work-stealing, 4 rows/batch) ----------
__global__ __launch_bounds__(256) void rescue2_kernel(
    const float* __restrict__ F, const float* __restrict__ C,
    const float* __restrict__ csq, const u32* __restrict__ cnt,
    const u32* __restrict__ list, u32* __restrict__ wptr, float* __restrict__ out)
{
    __shared__ float xs[4][512];
    __shared__ u64 wavemin[4][4];
    __shared__ int rows_s[4];

    const int tid = threadIdx.x;
    const int lane = tid & 63;
    const int wid = tid >> 6;
    const u32 n = cnt[0];

    for (;;) {
        __syncthreads();
        u32 base;
        if (tid == 0) {
            base = atomicAdd(wptr, 4u);
            rows_s[0] = (int)base;
        }
        __syncthreads();
        base = (u32)rows_s[0];
        if (base >= n) break;

        int rows[4];
#pragma unroll
        for (int j = 0; j < 4; ++j) {
            u32 idx = base + j;
            rows[j] = (int)list[idx < n ? idx : (n - 1)];
        }
#pragma unroll
        for (int j = 0; j < 4; ++j) {
            if (tid < 128)
                *(float4*)&xs[j][tid * 4] = *(const float4*)&F[(size_t)rows[j] * DIMS + tid * 4];
        }
        __syncthreads();

        float dot[4][4];
#pragma unroll
        for (int j = 0; j < 4; ++j)
#pragma unroll
            for (int q = 0; q < 4; ++q) dot[j][q] = 0.f;

#pragma unroll 4
        for (int d = 0; d < DIMS; ++d) {
            float cv[4];
#pragma unroll
            for (int q = 0; q < 4; ++q) cv[q] = C[d * KC + tid + 256 * q];
            float xv[4];
#pragma unroll
            for (int j = 0; j < 4; ++j) xv[j] = xs[j][d];
#pragma unroll
            for (int j = 0; j < 4; ++j)
#pragma unroll
                for (int q = 0; q < 4; ++q)
                    dot[j][q] = fmaf(xv[j], cv[q], dot[j][q]);
        }

#pragma unroll
        for (int j = 0; j < 4; ++j) {
            u64 best = ~0ull;
#pragma unroll
            for (int q = 0; q < 4; ++q) {
                const int k = tid + 256 * q;
                const float dist = csq[k] - 2.0f * dot[j][q];
                best = umin64(best, ((u64)f2o(dist) << 32) | (u32)k);
            }
#pragma unroll
            for (int off = 32; off > 0; off >>= 1)
                best = umin64(best, __shfl_xor(best, off, 64));
            if (lane == 0) wavemin[j][wid] = best;
        }
        __syncthreads();
        if (tid < 4) {
            const u32 idx = base + tid;
            if (idx < n) {
                u64 b = umin64(umin64(wavemin[tid][0], wavemin[tid][1]),
                               umin64(wavemin[tid][2], wavemin[tid][3]));
                out[list[idx]] = (float)(u32)(b & 0xFFFFFFFFull);
            }
        }
    }
}

// ================= fallback (fp32 vector path, used only if ws too small) =================
__global__ __launch_bounds__(256, 3) void assign_kernel_fp32(
    const float* __restrict__ F, const float* __restrict__ C,
    const float* __restrict__ csq, float* __restrict__ out)
{
    __shared__ float At[32][68];
    __shared__ float Bs[32 * 256];
    __shared__ u64 best_row[64];

    const int tid = threadIdx.x;
    const int tx = tid & 31;
    const int ty = tid >> 5;
    const int n0 = blockIdx.x * 64;

    if (tid < 64) best_row[tid] = ~0ull;

    u64 best[8];
#pragma unroll
    for (int r = 0; r < 8; ++r) best[r] = ~0ull;

    const int arow = tid >> 3;
    const int ac4  = tid & 7;
    const float* Atp = &At[0][ty * 8];
    const float* Bsp = &Bs[tx * 4];

    for (int kt = 0; kt < 4; ++kt) {
        float acc[8][8];
#pragma unroll
        for (int r = 0; r < 8; ++r)
#pragma unroll
            for (int j = 0; j < 8; ++j) acc[r][j] = 0.f;

        for (int dt = 0; dt < DIMS / 32; ++dt) {
            __syncthreads();
#pragma unroll
            for (int i = 0; i < 2; ++i) {
                int row = arow + 32 * i;
                float4 av = *(const float4*)&F[(long)(n0 + row) * DIMS + dt * 32 + ac4 * 4];
                At[ac4 * 4 + 0][row] = av.x;
                At[ac4 * 4 + 1][row] = av.y;
                At[ac4 * 4 + 2][row] = av.z;
                At[ac4 * 4 + 3][row] = av.w;
            }
#pragma unroll
            for (int i = 0; i < 8; ++i) {
                int idx = tid + 256 * i;
                int d  = idx >> 6;
                int c4 = idx & 63;
                float4 bv = *(const float4*)&C[(long)(dt * 32 + d) * KC + kt * 256 + c4 * 4];
                *(float4*)&Bs[d * 256 + c4 * 4] = bv;
            }
            __syncthreads();

#pragma unroll 8
            for (int dd = 0; dd < 32; ++dd) {
                float4 a0 = *(const float4*)(Atp + dd * 68);
                float4 a1 = *(const float4*)(Atp + dd * 68 + 4);
                float4 b0 = *(const float4*)(Bsp + dd * 256);
                float4 b1 = *(const float4*)(Bsp + dd * 256 + 128);
                float a[8] = {a0.x, a0.y, a0.z, a0.w, a1.x, a1.y, a1.z, a1.w};
                float bb[8] = {b0.x, b0.y, b0.z, b0.w, b1.x, b1.y, b1.z, b1.w};
#pragma unroll
                for (int r = 0; r < 8; ++r)
#pragma unroll
                    for (int j = 0; j < 8; ++j)
                        acc[r][j] = fmaf(a[r], bb[j], acc[r][j]);
            }
        }

        float4 cs0 = *(const float4*)&csq[kt * 256 + tx * 4];
        float4 cs1 = *(const float4*)&csq[kt * 256 + 128 + tx * 4];
        float cs[8] = {cs0.x, cs0.y, cs0.z, cs0.w, cs1.x, cs1.y, cs1.z, cs1.w};
#pragma unroll
        for (int j = 0; j < 8; ++j) {
            int k = kt * 256 + ((j < 4) ? (tx * 4 + j) : (128 + tx * 4 + (j - 4)));
#pragma unroll
            for (int r = 0; r < 8; ++r) {
                float val = cs[j] - 2.0f * acc[r][j];
                u64 key = ((u64)f2o(val) << 32) | (u64)(unsigned)k;
                if (key < best[r]) best[r] = key;
            }
        }
    }

#pragma unroll
    for (int r = 0; r < 8; ++r)
        atomicMin(&best_row[ty * 8 + r], best[r]);
    __syncthreads();

    if (tid < 64)
        out[n0 + tid] = (float)(unsigned)(best_row[tid] & 0xFFFFFFFFull);
}

// ================= launch =================
extern "C" void kernel_launch(void* const* d_in, const int* in_sizes, int n_in,
                              void* d_out, int out_size, void* d_ws, size_t ws_size,
                              hipStream_t stream) {
    const float* F = (const float*)d_in[0];   // [131072, 512]
    const float* C = (const float*)d_in[1];   // [512, 1024]
    float* out = (float*)d_out;               // [131072]
    char* ws = (char*)d_ws;

    if (ws_size < WS_NEEDED) {
        float* csq = (float*)d_ws;
        csq_kernel<<<KC / 256, 256, 0, stream>>>(C, csq);
        assign_kernel_fp32<<<NPTS / 64, 256, 0, stream>>>(F, C, csq, out);
        return;
    }

    u16* Ct = (u16*)(ws + CT_OFF);
    float* csq  = (float*)(ws + CSQ_OFF);
    float* csqp = (float*)(ws + CSQP_OFF);
    u32* cnt  = (u32*)(ws + CNT_OFF);
    u32* list = (u32*)(ws + LIST_OFF);

    hipMemsetAsync(cnt, 0, 8, stream);        // cnt[0] = list count, cnt[1] = rescue wptr
    split_c_kernel<<<dim3(KC / 32, DIMS / 32), 256, 0, stream>>>(C, Ct, csqp);
    csq_reduce_kernel<<<KC / 256, 256, 0, stream>>>(csqp, csq);
    gemm_argmin_kernel<<<NPTS / 128, 512, 131072, stream>>>(F, Ct, csq, out, cnt, list);
    rescue2_kernel<<<1024, 256, 0, stream>>>(F, C, csq, cnt, list, cnt + 1, out);
}